// Round 6
// baseline (1379.435 us; speedup 1.0000x reference)
//
#include <hip/hip_runtime.h>
#include <hip/hip_bf16.h>

typedef unsigned short u16;
typedef unsigned int u32;
typedef __bf16 bf16x8 __attribute__((ext_vector_type(8)));
typedef float f32x4 __attribute__((ext_vector_type(4)));

#define E_ 8
#define H_ 2048
#define D_ 2048
#define T_ 2048
#define N2_ 4096

__device__ __forceinline__ u16 f2bf(float f) {
    unsigned u = __builtin_bit_cast(unsigned, f);
    unsigned r = (u + 0x7FFFu + ((u >> 16) & 1u)) >> 16;
    return (u16)r;
}

typedef __attribute__((address_space(1))) const void* gptr_t;
typedef __attribute__((address_space(3))) void* lptr_t;
__device__ __forceinline__ void gload16(const void* g, void* l) {
    // async global->LDS, 16B/lane; LDS dest = wave-uniform base + lane*16
    __builtin_amdgcn_global_load_lds((gptr_t)g, (lptr_t)l, 16, 0, 0);
}

// R6 structure (AITER-style): A staged through double-buffered LDS
// (16KB/buf, XOR-swizzled chunks -> ds_read_b128 conflict-free, verified
// R4/R5: SQ_LDS_BANK_CONFLICT=0); B fragments streamed DIRECTLY from
// global to VGPRs in MFMA layout (16 rows x 64B per load instr), served
// by the per-XCD L2 via the R5 grid swizzle (FETCH 541->199MB verified).
// One __syncthreads per K-step; vmcnt drain hides behind ~2480 cyc MFMA.
// R3 lesson: keep the 2-wave/EU register budget (no launch_bounds,3).

// ---------------- conversion / transpose pre-pass ----------------

__global__ __launch_bounds__(256) void k_convert_x(const float4* __restrict__ x,
                                                   ushort4* __restrict__ xb) {
    int i = blockIdx.x * 256 + threadIdx.x;   // exactly T_*H_/4 threads
    float4 v = x[i];
    ushort4 o;
    o.x = f2bf(v.x); o.y = f2bf(v.y); o.z = f2bf(v.z); o.w = f2bf(v.w);
    xb[i] = o;
}

// gate_up_w fp32 [E][H][2D] -> wgT,wuT bf16 [E][D][H]  (transpose + de-interleave)
// Coalesced reads: each wave reads full 512B row segments.
__global__ __launch_bounds__(256) void k_tr_gateup(const float* __restrict__ w,
                                                   u16* __restrict__ wgT,
                                                   u16* __restrict__ wuT) {
    // packed pairs: word d2 holds d=2*d2 (lo16) and d=2*d2+1 (hi16)
    __shared__ u32 Gs[32 * 65];
    __shared__ u32 Us[32 * 65];
    const int e = blockIdx.z, h0 = blockIdx.x * 64, c0 = blockIdx.y * 128;
    const int tid = threadIdx.x;
    {
        const int hl = tid >> 5;              // 0..7
        const int c4 = (tid & 31) * 4;        // fp32 col within 128 (even)
#pragma unroll
        for (int q = 0; q < 8; q++) {
            int h = q * 8 + hl;
            float4 v = *(const float4*)(w + ((size_t)e * H_ + h0 + h) * N2_ + c0 + c4);
            // cols c4,c4+1 -> d=c4/2 (g,u); c4+2,c4+3 -> d=c4/2+1
            int d2 = c4 >> 2;                 // pair index 0..31
            Gs[d2 * 65 + h] = (u32)f2bf(v.x) | ((u32)f2bf(v.z) << 16);
            Us[d2 * 65 + h] = (u32)f2bf(v.y) | ((u32)f2bf(v.w) << 16);
        }
    }
    __syncthreads();
    {
        const int dl = tid >> 2;              // 0..63
        const int hseg = (tid & 3) * 16;
        const int sh = (dl & 1) * 16;
        u16 vg[16] __attribute__((aligned(16)));
        u16 vu[16] __attribute__((aligned(16)));
#pragma unroll
        for (int j = 0; j < 16; j++) {
            vg[j] = (u16)(Gs[(dl >> 1) * 65 + hseg + j] >> sh);
            vu[j] = (u16)(Us[(dl >> 1) * 65 + hseg + j] >> sh);
        }
        size_t ob = ((size_t)e * D_ + (c0 >> 1) + dl) * H_ + h0 + hseg;
        *(uint4*)&wgT[ob]     = *(const uint4*)&vg[0];
        *(uint4*)&wgT[ob + 8] = *(const uint4*)&vg[8];
        *(uint4*)&wuT[ob]     = *(const uint4*)&vu[0];
        *(uint4*)&wuT[ob + 8] = *(const uint4*)&vu[8];
    }
}

// down_w fp32 [E][D][H] -> wdT bf16 [E][H][D]  (transpose)
// Coalesced reads: thread owns a 4(d) x 4(h) block; 16 threads cover 256B/row.
__global__ __launch_bounds__(256) void k_tr_down(const float* __restrict__ w,
                                                 u16* __restrict__ wdT) {
    __shared__ u16 Ts[64 * 76];               // [h][d], pad 76
    const int e = blockIdx.z, d0 = blockIdx.x * 64, h0 = blockIdx.y * 64;
    const int tid = threadIdx.x;
    {
        const int dg = tid >> 4;              // 0..15 -> rows dg*4..+3
        const int c4 = (tid & 15) * 4;        // h col
        float4 v0 = *(const float4*)(w + ((size_t)e * D_ + d0 + dg * 4 + 0) * H_ + h0 + c4);
        float4 v1 = *(const float4*)(w + ((size_t)e * D_ + d0 + dg * 4 + 1) * H_ + h0 + c4);
        float4 v2 = *(const float4*)(w + ((size_t)e * D_ + d0 + dg * 4 + 2) * H_ + h0 + c4);
        float4 v3 = *(const float4*)(w + ((size_t)e * D_ + d0 + dg * 4 + 3) * H_ + h0 + c4);
        u16 t[4][4] __attribute__((aligned(8)));
        t[0][0] = f2bf(v0.x); t[0][1] = f2bf(v1.x); t[0][2] = f2bf(v2.x); t[0][3] = f2bf(v3.x);
        t[1][0] = f2bf(v0.y); t[1][1] = f2bf(v1.y); t[1][2] = f2bf(v2.y); t[1][3] = f2bf(v3.y);
        t[2][0] = f2bf(v0.z); t[2][1] = f2bf(v1.z); t[2][2] = f2bf(v2.z); t[2][3] = f2bf(v3.z);
        t[3][0] = f2bf(v0.w); t[3][1] = f2bf(v1.w); t[3][2] = f2bf(v2.w); t[3][3] = f2bf(v3.w);
#pragma unroll
        for (int i = 0; i < 4; i++)
            *(uint2*)&Ts[(c4 + i) * 76 + dg * 4] = *(const uint2*)&t[i][0];
    }
    __syncthreads();
    {
        const int hl = tid >> 2;
        const int dseg = (tid & 3) * 16;
        u16 vd[16] __attribute__((aligned(16)));
#pragma unroll
        for (int j = 0; j < 16; j++) vd[j] = Ts[hl * 76 + dseg + j];
        size_t ob = ((size_t)e * H_ + h0 + hl) * D_ + d0 + dseg;
        *(uint4*)&wdT[ob]     = *(const uint4*)&vd[0];
        *(uint4*)&wdT[ob + 8] = *(const uint4*)&vd[8];
    }
}

// ---------------- GEMM 1: gate_up + GLU epilogue (rw folded in) ----------------
// fused[e][t][d] = rw[t][e] * (clip(up,-7,7)+1) * glu(min(gate,7))

__global__ __launch_bounds__(256, 2) void k_gemm_gateup(
    const u16* __restrict__ xb,    // [T][H] bf16
    const u16* __restrict__ wgT,   // [E][D][H] bf16
    const u16* __restrict__ wuT,   // [E][D][H] bf16
    const float* __restrict__ gub, // [E][2D] fp32 interleaved
    const float* __restrict__ rw,  // [T][E] fp32
    u16* __restrict__ fused)       // [E][T][D] bf16
{
    // XCD swizzle (R5): XCD k owns d-tiles {2k,2k+1} for all e; t fastest.
    const int id = blockIdx.x;
    const int xcd = id & 7;
    const int local = id >> 3;
    const int e = local >> 5;
    const int rem = local & 31;
    const int t0 = (rem & 15) * 128;
    const int d0 = (xcd * 2 + (rem >> 4)) * 128;

    __shared__ u16 As[2][128 * 64];

    const int tid = threadIdx.x;
    const int lane = tid & 63;
    const int wave = tid >> 6;
    const int wr = (wave >> 1) * 64;
    const int wc = (wave & 1) * 64;
    const int l16 = lane & 15;
    const int quad = lane >> 4;

    f32x4 accg[4][4], accu[4][4];
    const f32x4 vzero = {0.f, 0.f, 0.f, 0.f};
#pragma unroll
    for (int i = 0; i < 4; i++)
#pragma unroll
        for (int j = 0; j < 4; j++) { accg[i][j] = vzero; accu[i][j] = vzero; }

    const u16* Ag = xb + (size_t)t0 * H_;
    // B row base pointers (MFMA fragment layout: n = wc + j*16 + l16)
    const u16* Bgr[4];
    const u16* Bur[4];
#pragma unroll
    for (int j = 0; j < 4; j++) {
        size_t row = (size_t)e * D_ + d0 + wc + j * 16 + l16;
        Bgr[j] = wgT + row * H_ + quad * 8;
        Bur[j] = wuT + row * H_ + quad * 8;
    }

    // A staging: swizzled (verified conflict-free)
    const int sr = lane >> 3;
    const int csrc = ((lane & 7) ^ sr) * 8;

    // prefetch k0=0 into buffer 0 (one gload16 per wave per chunk of 8 rows)
#pragma unroll
    for (int c = 0; c < 4; c++) {
        const int R = wave * 32 + c * 8;
        gload16(Ag + (size_t)(R + sr) * H_ + csrc, &As[0][R * 64]);
    }

    int p = 0;
    for (int k0 = 0; k0 < H_; k0 += 64) {
        __syncthreads();   // own vmcnt(0) drain + barrier: As[p] staged, As[p^1] free
        if (k0 + 64 < H_) {
#pragma unroll
            for (int c = 0; c < 4; c++) {
                const int R = wave * 32 + c * 8;
                gload16(Ag + (size_t)(R + sr) * H_ + (k0 + 64) + csrc, &As[p ^ 1][R * 64]);
            }
        }
#pragma unroll
        for (int kk = 0; kk < 2; kk++) {
            const int pco = (((kk << 2) | quad) ^ (l16 & 7)) * 8;
            bf16x8 af[4], bg[4], bu[4];
#pragma unroll
            for (int j = 0; j < 4; j++) {
                bg[j] = *(const bf16x8*)(Bgr[j] + k0 + kk * 32);
                bu[j] = *(const bf16x8*)(Bur[j] + k0 + kk * 32);
            }
#pragma unroll
            for (int i = 0; i < 4; i++)
                af[i] = *(const bf16x8*)&As[p][(wr + i * 16 + l16) * 64 + pco];
#pragma unroll
            for (int i = 0; i < 4; i++)
#pragma unroll
                for (int j = 0; j < 4; j++) {
                    accg[i][j] = __builtin_amdgcn_mfma_f32_16x16x32_bf16(af[i], bg[j], accg[i][j], 0, 0, 0);
                    accu[i][j] = __builtin_amdgcn_mfma_f32_16x16x32_bf16(af[i], bu[j], accu[i][j], 0, 0, 0);
                }
        }
        p ^= 1;
    }

    // epilogue: bias + clamp + GLU, scale by routing weight, write bf16
#pragma unroll
    for (int j = 0; j < 4; j++) {
        const int col = d0 + wc + j * 16 + l16;
        const float bgv = gub[e * N2_ + 2 * col];
        const float buv = gub[e * N2_ + 2 * col + 1];
#pragma unroll
        for (int i = 0; i < 4; i++) {
#pragma unroll
            for (int r = 0; r < 4; r++) {
                int row = t0 + wr + i * 16 + quad * 4 + r;
                float g = accg[i][j][r] + bgv;
                float u = accu[i][j][r] + buv;
                g = fminf(g, 7.0f);
                u = fminf(fmaxf(u, -7.0f), 7.0f);
                float glu = g / (1.0f + __expf(-1.702f * g));
                float f = (u + 1.0f) * glu * rw[row * E_ + e];
                fused[((size_t)e * T_ + row) * D_ + col] = f2bf(f);
            }
        }
    }
}

// ---------------- GEMM 2: down proj, experts-in-K, 128x256 tile, no atomics ----
// pout[g][t][h] = sum_{e in pair g} fused[e][t][:] @ wdT[e][h][:]

__global__ __launch_bounds__(256, 2) void k_gemm_down(
    const u16* __restrict__ fused, // [E][T][D] bf16 (rw-scaled)
    const u16* __restrict__ wdT,   // [E][H][D] bf16
    float* __restrict__ pout)      // [4][T][H] fp32 partials
{
    // XCD swizzle (R5): XCD k owns h-tile k (256 cols); t fastest.
    const int id = blockIdx.x;
    const int xcd = id & 7;
    const int local = id >> 3;
    const int g = local >> 4;
    const int t0 = (local & 15) * 128;
    const int h0 = xcd * 256;

    __shared__ u16 As[2][128 * 64];

    const int tid = threadIdx.x;
    const int lane = tid & 63;
    const int wave = tid >> 6;
    const int wr = (wave >> 1) * 64;
    const int wc = (wave & 1) * 64;
    const int l16 = lane & 15;
    const int quad = lane >> 4;

    f32x4 acc0[4][4], acc1[4][4];
    const f32x4 vzero = {0.f, 0.f, 0.f, 0.f};
#pragma unroll
    for (int i = 0; i < 4; i++)
#pragma unroll
        for (int j = 0; j < 4; j++) { acc0[i][j] = vzero; acc1[i][j] = vzero; }

    const int sr = lane >> 3;
    const int csrc = ((lane & 7) ^ sr) * 8;

    // flattened 64 K-steps: step s -> expert g*2 + (s>>5), k0 = (s&31)*64
    const u16* Abase[2] = { fused + ((size_t)(g * 2 + 0) * T_ + t0) * D_,
                            fused + ((size_t)(g * 2 + 1) * T_ + t0) * D_ };
    // B row bases per expert (n = h0 + wc + j*16 + l16, plus +128 set)
    const u16* B0r[2][4];
    const u16* B1r[2][4];
#pragma unroll
    for (int ee = 0; ee < 2; ee++)
#pragma unroll
        for (int j = 0; j < 4; j++) {
            size_t row0 = (size_t)(g * 2 + ee) * H_ + h0 + wc + j * 16 + l16;
            B0r[ee][j] = wdT + row0 * D_ + quad * 8;
            B1r[ee][j] = wdT + (row0 + 128) * D_ + quad * 8;
        }

    // prefetch step 0
#pragma unroll
    for (int c = 0; c < 4; c++) {
        const int R = wave * 32 + c * 8;
        gload16(Abase[0] + (size_t)(R + sr) * D_ + csrc, &As[0][R * 64]);
    }

    int p = 0;
    for (int s = 0; s < 64; s++) {
        const int ee = s >> 5;
        const int k0 = (s & 31) * 64;
        __syncthreads();
        if (s + 1 < 64) {
            const u16* An = Abase[(s + 1) >> 5];
            const int kn = ((s + 1) & 31) * 64;
#pragma unroll
            for (int c = 0; c < 4; c++) {
                const int R = wave * 32 + c * 8;
                gload16(An + (size_t)(R + sr) * D_ + kn + csrc, &As[p ^ 1][R * 64]);
            }
        }
#pragma unroll
        for (int kk = 0; kk < 2; kk++) {
            const int pco = (((kk << 2) | quad) ^ (l16 & 7)) * 8;
            bf16x8 af[4], b0[4], b1[4];
#pragma unroll
            for (int j = 0; j < 4; j++) {
                b0[j] = *(const bf16x8*)(B0r[ee][j] + k0 + kk * 32);
                b1[j] = *(const bf16x8*)(B1r[ee][j] + k0 + kk * 32);
            }
#pragma unroll
            for (int i = 0; i < 4; i++)
                af[i] = *(const bf16x8*)&As[p][(wr + i * 16 + l16) * 64 + pco];
#pragma unroll
            for (int i = 0; i < 4; i++)
#pragma unroll
                for (int j = 0; j < 4; j++) {
                    acc0[i][j] = __builtin_amdgcn_mfma_f32_16x16x32_bf16(af[i], b0[j], acc0[i][j], 0, 0, 0);
                    acc1[i][j] = __builtin_amdgcn_mfma_f32_16x16x32_bf16(af[i], b1[j], acc1[i][j], 0, 0, 0);
                }
        }
        p ^= 1;
    }

    float* po = pout + (size_t)g * T_ * H_;
#pragma unroll
    for (int i = 0; i < 4; i++) {
#pragma unroll
        for (int r = 0; r < 4; r++) {
            int row = t0 + wr + i * 16 + quad * 4 + r;
#pragma unroll
            for (int j = 0; j < 4; j++) {
                int col0 = h0 + wc + j * 16 + l16;
                po[(size_t)row * H_ + col0]       = acc0[i][j][r];
                po[(size_t)row * H_ + col0 + 128] = acc1[i][j][r];
            }
        }
    }
}

// out[t][h] = sum_g pout[g] + sum_e rw[t][e] * down_b[e][h]   (float4)
__global__ __launch_bounds__(256) void k_combine(const float4* __restrict__ p,
                                                 const float* __restrict__ rw,
                                                 const float4* __restrict__ db,
                                                 float4* __restrict__ out) {
    int i = blockIdx.x * 256 + threadIdx.x;   // T_*H_/4 elements
    int t = i >> 9;
    int h4 = i & 511;
    const size_t TH4 = (size_t)T_ * H_ / 4;
    float4 s0 = p[i], s1 = p[i + TH4], s2 = p[i + 2 * TH4], s3 = p[i + 3 * TH4];
    float4 a;
    a.x = s0.x + s1.x + s2.x + s3.x;
    a.y = s0.y + s1.y + s2.y + s3.y;
    a.z = s0.z + s1.z + s2.z + s3.z;
    a.w = s0.w + s1.w + s2.w + s3.w;
#pragma unroll
    for (int e = 0; e < E_; e++) {
        float w = rw[t * E_ + e];
        float4 b = db[e * (H_ / 4) + h4];
        a.x += w * b.x; a.y += w * b.y; a.z += w * b.z; a.w += w * b.w;
    }
    out[i] = a;
}

// ---------------- launch ----------------

extern "C" void kernel_launch(void* const* d_in, const int* in_sizes, int n_in,
                              void* d_out, int out_size, void* d_ws, size_t ws_size,
                              hipStream_t stream) {
    const float* x   = (const float*)d_in[0];   // [B,S,H]
    const float* rw  = (const float*)d_in[1];   // [T,E]
    const float* guw = (const float*)d_in[2];   // [E,H,2D]
    const float* gub = (const float*)d_in[3];   // [E,2D]
    const float* dww = (const float*)d_in[4];   // [E,D,H]
    const float* dwb = (const float*)d_in[5];   // [E,H]
    float* out = (float*)d_out;

    char* ws = (char*)d_ws;
    u16* xb    = (u16*)(ws);                      //  8 MB  [T][H]
    u16* wgT   = (u16*)(ws + 8388608);            // 64 MB  [E][D][H]
    u16* wuT   = (u16*)(ws + 75497472);           // 64 MB  [E][D][H]
    u16* wdT   = (u16*)(ws + 142606336);          // 64 MB  [E][H][D]
    u16* fused = (u16*)(ws + 209715200);          // 64 MB  [E][T][D]
    // pout (64 MB fp32 [4][T][H]) reuses the wgT region — wgT is dead after
    // k_gemm_gateup; the stream serializes gateup -> down -> combine.
    float* pout = (float*)(ws + 8388608);

    k_convert_x<<<dim3((T_ * H_) / 4 / 256), 256, 0, stream>>>((const float4*)x, (ushort4*)xb);
    k_tr_gateup<<<dim3(H_ / 64, N2_ / 128, E_), 256, 0, stream>>>(guw, wgT, wuT);
    k_tr_down<<<dim3(D_ / 64, H_ / 64, E_), 256, 0, stream>>>(dww, wdT);
    k_gemm_gateup<<<dim3(2048), 256, 0, stream>>>(xb, wgT, wuT, gub, rw, fused);
    k_gemm_down<<<dim3(512), 256, 0, stream>>>(fused, wdT, pout);
    k_combine<<<dim3((T_ * H_) / 4 / 256), 256, 0, stream>>>((const float4*)pout, rw, (const float4*)dwb, (float4*)out);
}